// Round 2
// baseline (5226.041 us; speedup 1.0000x reference)
//
#include <hip/hip_runtime.h>

// Problem constants (match reference)
constexpr int NGPH = 128;            // graphs per batch
constexpr int NPG  = 1024;           // nodes per graph
constexpr int NN   = NGPH * NPG;     // 131072 nodes
constexpr int HD   = 128;            // feature width (FIN == H == 128)
constexpr int EPG  = 16384;          // edges per graph (E // B), contiguous per graph
constexpr int KS1 = 820, KS2 = 656, KS3 = 525;

// ---------------------------------------------------------------------------
// init: alive mask = 1.0 for all nodes (ws is poisoned 0xAA before each call)
__global__ __launch_bounds__(256) void init_alive(float* __restrict__ alive) {
  int i = blockIdx.x * 256 + threadIdx.x;
  if (i < NN) alive[i] = 1.0f;
}

// ---------------------------------------------------------------------------
// deg[i] = sum over incoming edges of alive[src]  (denominator of mean)
__global__ __launch_bounds__(256) void deg_kernel(const int* __restrict__ src,
                                                  const int* __restrict__ dst,
                                                  const float* __restrict__ alive,
                                                  float* __restrict__ deg) {
  __shared__ float dacc[NPG];
  int g = blockIdx.x, t = threadIdx.x;
  for (int i = t; i < NPG; i += 256) dacc[i] = 0.f;
  __syncthreads();
  int eb = g * EPG;
  for (int i = t; i < EPG; i += 256) {
    int s = src[eb + i];
    int d = dst[eb + i] - (g << 10);
    atomicAdd(&dacc[d], alive[s]);
  }
  __syncthreads();
  for (int i = t; i < NPG; i += 256) deg[(g << 10) + i] = dacc[i];
}

// ---------------------------------------------------------------------------
// S[dst, :] = sum over incoming edges of X[src, :].
// One block per (graph, 16-feature chunk). LDS accumulator 1024x16 = 64 KB,
// swizzled (f+r)&15 so an edge's 16 lanes hit 16 distinct banks.
// X rows of pruned nodes are exactly 0, so no edge-mask multiply is needed.
__global__ __launch_bounds__(512) void agg_kernel(const float* __restrict__ X,
                                                  const int* __restrict__ src,
                                                  const int* __restrict__ dst,
                                                  float* __restrict__ S) {
  __shared__ float acc[NPG * 16];   // exactly 64 KB
  int g  = blockIdx.x >> 3;
  int f0 = (blockIdx.x & 7) * 16;
  int t  = threadIdx.x;
  for (int i = t; i < NPG * 16; i += 512) acc[i] = 0.f;
  __syncthreads();
  int f = t & 15, slot = t >> 4;     // 32 edges in flight per iteration
  int eb = g * EPG;
  for (int i = slot; i < EPG; i += 32) {
    int s = src[eb + i];
    int r = dst[eb + i] - (g << 10);
    float v = X[(size_t)s * HD + f0 + f];
    atomicAdd(&acc[(r << 4) + ((f + r) & 15)], v);
  }
  __syncthreads();
  for (int i = t; i < NPG * 16; i += 512) {
    int r = i >> 4, ff = i & 15;
    S[(size_t)((g << 10) + r) * HD + f0 + ff] = acc[(r << 4) + ((ff + r) & 15)];
  }
}

// ---------------------------------------------------------------------------
// Hout = relu( (S/max(deg,1)) @ Wl^T + X @ Wr^T + bl ), in-place safe on S
// (each block reads/writes only its own 128 rows). 128x128 tile, 8x8 micro.
__global__ __launch_bounds__(256) void gemm_kernel(const float* __restrict__ S,
                                                   const float* __restrict__ deg,
                                                   const float* __restrict__ X,
                                                   const float* __restrict__ Wl,
                                                   const float* __restrict__ Wr,
                                                   const float* __restrict__ bl,
                                                   float* __restrict__ Hout) {
  __shared__ __align__(16) float ATm[16][HD];  // mean, transposed [k][row]
  __shared__ __align__(16) float ATx[16][HD];  // x,    transposed [k][row]
  __shared__ __align__(16) float WTl[16][HD];  // Wl,   transposed [k][col]
  __shared__ __align__(16) float WTr[16][HD];  // Wr,   transposed [k][col]
  int t  = threadIdx.x;
  int r0 = blockIdx.x * 128;
  int tc = t & 15, tr = t >> 4;       // col group (x8), row group (x8)
  int sr = t & 127, sq = t >> 7;      // staging: row/col index + half select
  float invd = 1.0f / fmaxf(deg[r0 + sr], 1.0f);
  float acc[8][8];
#pragma unroll
  for (int i = 0; i < 8; ++i)
#pragma unroll
    for (int j = 0; j < 8; ++j) acc[i][j] = 0.f;

  for (int c0 = 0; c0 < HD; c0 += 16) {
    // stage A tiles (128 rows x 16 k), transposed
#pragma unroll
    for (int j = 0; j < 2; ++j) {
      int k = (sq * 2 + j) * 4;
      float4 vs = *(const float4*)&S[(size_t)(r0 + sr) * HD + c0 + k];
      ATm[k + 0][sr] = vs.x * invd; ATm[k + 1][sr] = vs.y * invd;
      ATm[k + 2][sr] = vs.z * invd; ATm[k + 3][sr] = vs.w * invd;
      float4 vx = *(const float4*)&X[(size_t)(r0 + sr) * HD + c0 + k];
      ATx[k + 0][sr] = vx.x; ATx[k + 1][sr] = vx.y;
      ATx[k + 2][sr] = vx.z; ATx[k + 3][sr] = vx.w;
    }
    // stage W tiles (128 cols x 16 k), transposed
    {
      int kb = sq * 8;
      float4 w0 = *(const float4*)&Wl[sr * HD + c0 + kb];
      float4 w1 = *(const float4*)&Wl[sr * HD + c0 + kb + 4];
      WTl[kb + 0][sr] = w0.x; WTl[kb + 1][sr] = w0.y;
      WTl[kb + 2][sr] = w0.z; WTl[kb + 3][sr] = w0.w;
      WTl[kb + 4][sr] = w1.x; WTl[kb + 5][sr] = w1.y;
      WTl[kb + 6][sr] = w1.z; WTl[kb + 7][sr] = w1.w;
      float4 u0 = *(const float4*)&Wr[sr * HD + c0 + kb];
      float4 u1 = *(const float4*)&Wr[sr * HD + c0 + kb + 4];
      WTr[kb + 0][sr] = u0.x; WTr[kb + 1][sr] = u0.y;
      WTr[kb + 2][sr] = u0.z; WTr[kb + 3][sr] = u0.w;
      WTr[kb + 4][sr] = u1.x; WTr[kb + 5][sr] = u1.y;
      WTr[kb + 6][sr] = u1.z; WTr[kb + 7][sr] = u1.w;
    }
    __syncthreads();
#pragma unroll
    for (int k = 0; k < 16; ++k) {
      float am[8], ax[8], wl[8], wr[8];
      *(float4*)&am[0] = *(const float4*)&ATm[k][tr * 8];
      *(float4*)&am[4] = *(const float4*)&ATm[k][tr * 8 + 4];
      *(float4*)&ax[0] = *(const float4*)&ATx[k][tr * 8];
      *(float4*)&ax[4] = *(const float4*)&ATx[k][tr * 8 + 4];
      *(float4*)&wl[0] = *(const float4*)&WTl[k][tc * 8];
      *(float4*)&wl[4] = *(const float4*)&WTl[k][tc * 8 + 4];
      *(float4*)&wr[0] = *(const float4*)&WTr[k][tc * 8];
      *(float4*)&wr[4] = *(const float4*)&WTr[k][tc * 8 + 4];
#pragma unroll
      for (int i = 0; i < 8; ++i)
#pragma unroll
        for (int j = 0; j < 8; ++j)
          acc[i][j] += am[i] * wl[j] + ax[i] * wr[j];
    }
    __syncthreads();
  }
  float4 b0 = *(const float4*)&bl[tc * 8];
  float4 b1 = *(const float4*)&bl[tc * 8 + 4];
  float bv[8] = {b0.x, b0.y, b0.z, b0.w, b1.x, b1.y, b1.z, b1.w};
#pragma unroll
  for (int i = 0; i < 8; ++i) {
    size_t row = (size_t)(r0 + tr * 8 + i);
    float4 o0, o1;
    o0.x = fmaxf(acc[i][0] + bv[0], 0.f); o0.y = fmaxf(acc[i][1] + bv[1], 0.f);
    o0.z = fmaxf(acc[i][2] + bv[2], 0.f); o0.w = fmaxf(acc[i][3] + bv[3], 0.f);
    o1.x = fmaxf(acc[i][4] + bv[4], 0.f); o1.y = fmaxf(acc[i][5] + bv[5], 0.f);
    o1.z = fmaxf(acc[i][6] + bv[6], 0.f); o1.w = fmaxf(acc[i][7] + bv[7], 0.f);
    *(float4*)&Hout[row * HD + tc * 8]     = o0;
    *(float4*)&Hout[row * HD + tc * 8 + 4] = o1;
  }
}

// ---------------------------------------------------------------------------
// Per-graph: score = (H.wp)/||wp||, bitonic-sort masked scores, threshold at
// kth largest, gate kept rows by tanh(score), zero the rest, update alive.
__global__ __launch_bounds__(256) void topk_kernel(const float* __restrict__ Hbuf,
                                                   float* __restrict__ Xout,
                                                   float* __restrict__ alive,
                                                   const float* __restrict__ wp,
                                                   int kk) {
  __shared__ float wps[HD];
  __shared__ float sc[NPG];
  __shared__ float srt[NPG];
  __shared__ float shv[1];
  int g = blockIdx.x, t = threadIdx.x;
  if (t < HD) wps[t] = wp[t];
  __syncthreads();
  if (t == 0) {
    float ss = 0.f;
    for (int i = 0; i < HD; ++i) ss += wps[i] * wps[i];
    shv[0] = 1.0f / (sqrtf(ss) + 1e-16f);
  }
  __syncthreads();
  float inv = shv[0];
  size_t gbase = (size_t)g * NPG * HD;
#pragma unroll
  for (int q = 0; q < 4; ++q) {
    int n = t + q * 256;
    const float* row = &Hbuf[gbase + (size_t)n * HD];
    float s = 0.f;
    for (int c = 0; c < HD; c += 4) {
      float4 h4 = *(const float4*)&row[c];
      s += h4.x * wps[c] + h4.y * wps[c + 1] + h4.z * wps[c + 2] + h4.w * wps[c + 3];
    }
    s *= inv;
    sc[n] = s;
    srt[n] = (alive[(g << 10) + n] > 0.5f) ? s : -3.402823466e38f;
  }
  __syncthreads();
  // bitonic ascending sort of srt[0..1023]
  for (int k2 = 2; k2 <= NPG; k2 <<= 1) {
    for (int j = k2 >> 1; j > 0; j >>= 1) {
#pragma unroll
      for (int q = 0; q < 4; ++q) {
        int i = t + q * 256;
        int l = i ^ j;
        if (l > i) {
          float a = srt[i], b = srt[l];
          if ((a > b) == ((i & k2) == 0)) { srt[i] = b; srt[l] = a; }
        }
      }
      __syncthreads();
    }
  }
  float thr = srt[NPG - kk];   // kth-largest alive score
#pragma unroll
  for (int q = 0; q < 4; ++q) {
    int n = t + q * 256;
    float s = sc[n];
    bool isal = alive[(g << 10) + n] > 0.5f;
    bool sel = isal && (s >= thr);
    float gt = sel ? tanhf(s) : 0.f;
    const float* row = &Hbuf[gbase + (size_t)n * HD];
    float* orow = &Xout[gbase + (size_t)n * HD];
    for (int c = 0; c < HD; c += 4) {
      float4 h4 = *(const float4*)&row[c];
      float4 o = make_float4(h4.x * gt, h4.y * gt, h4.z * gt, h4.w * gt);
      *(float4*)&orow[c] = o;
    }
    alive[(g << 10) + n] = sel ? 1.f : 0.f;
  }
}

// ---------------------------------------------------------------------------
// global mean pool (divisor exactly K3), 2-layer MLP, log_softmax
__global__ __launch_bounds__(128) void final_kernel(const float* __restrict__ X,
                                                    const float* __restrict__ Wf1,
                                                    const float* __restrict__ bf1,
                                                    const float* __restrict__ Wf2,
                                                    const float* __restrict__ bf2,
                                                    float* __restrict__ out) {
  __shared__ float pl[HD];
  __shared__ float h1[64];
  __shared__ float lg[10];
  __shared__ float red[2];
  int g = blockIdx.x, t = threadIdx.x;
  size_t base = (size_t)g * NPG * HD;
  float s = 0.f;
  for (int r = 0; r < NPG; ++r) s += X[base + (size_t)r * HD + t];
  pl[t] = s / (float)KS3;
  __syncthreads();
  if (t < 64) {
    float h = bf1[t];
    for (int f = 0; f < HD; ++f) h += pl[f] * Wf1[t * HD + f];
    h1[t] = fmaxf(h, 0.f);
  }
  __syncthreads();
  if (t < 10) {
    float z = bf2[t];
    for (int j = 0; j < 64; ++j) z += h1[j] * Wf2[t * 64 + j];
    lg[t] = z;
  }
  __syncthreads();
  if (t == 0) {
    float m = lg[0];
    for (int c = 1; c < 10; ++c) m = fmaxf(m, lg[c]);
    float ssum = 0.f;
    for (int c = 0; c < 10; ++c) ssum += expf(lg[c] - m);
    red[0] = m; red[1] = logf(ssum);
  }
  __syncthreads();
  if (t < 10) out[g * 10 + t] = lg[t] - red[0] - red[1];
}

// ---------------------------------------------------------------------------
extern "C" void kernel_launch(void* const* d_in, const int* in_sizes, int n_in,
                              void* d_out, int out_size, void* d_ws, size_t ws_size,
                              hipStream_t stream) {
  const float* x  = (const float*)d_in[0];
  const int* ei   = (const int*)d_in[1];
  const int* src  = ei;
  const int* dst  = ei + (size_t)NGPH * EPG;
  const float* Wl[3]  = {(const float*)d_in[2], (const float*)d_in[6],  (const float*)d_in[10]};
  const float* blv[3] = {(const float*)d_in[3], (const float*)d_in[7],  (const float*)d_in[11]};
  const float* Wr[3]  = {(const float*)d_in[4], (const float*)d_in[8],  (const float*)d_in[12]};
  const float* wp[3]  = {(const float*)d_in[5], (const float*)d_in[9],  (const float*)d_in[13]};
  const float* Wf1 = (const float*)d_in[14];
  const float* bf1 = (const float*)d_in[15];
  const float* Wf2 = (const float*)d_in[16];
  const float* bf2 = (const float*)d_in[17];
  float* out = (float*)d_out;

  // workspace layout: bufA (64MB) | bufB (64MB) | deg (512KB) | alive (512KB)
  float* bufA  = (float*)d_ws;
  float* bufB  = bufA + (size_t)NN * HD;
  float* degb  = bufB + (size_t)NN * HD;
  float* alive = degb + NN;

  const int kks[3] = {KS1, KS2, KS3};

  init_alive<<<NN / 256, 256, 0, stream>>>(alive);
  const float* Xin = x;
  for (int l = 0; l < 3; ++l) {
    deg_kernel<<<NGPH, 256, 0, stream>>>(src, dst, alive, degb);
    agg_kernel<<<NGPH * 8, 512, 0, stream>>>(Xin, src, dst, bufB);
    gemm_kernel<<<NN / 128, 256, 0, stream>>>(bufB, degb, Xin, Wl[l], Wr[l], blv[l], bufB);
    topk_kernel<<<NGPH, 256, 0, stream>>>(bufB, bufA, alive, wp[l], kks[l]);
    Xin = bufA;
  }
  final_kernel<<<NGPH, 128, 0, stream>>>(bufA, Wf1, bf1, Wf2, bf2, out);
}

// Round 3
// 1408.088 us; speedup vs baseline: 3.7114x; 3.7114x over previous
//
#include <hip/hip_runtime.h>

// Problem constants (match reference)
constexpr int NGPH = 128;            // graphs per batch
constexpr int NPG  = 1024;           // nodes per graph
constexpr int NN   = NGPH * NPG;     // 131072 nodes
constexpr int HD   = 128;            // feature width (FIN == H == 128)
constexpr int EPG  = 16384;          // edges per graph (E // B), contiguous per graph
constexpr int KS1 = 820, KS2 = 656, KS3 = 525;

// ---------------------------------------------------------------------------
// init: alive mask = 1.0 for all nodes (ws is poisoned 0xAA before each call)
__global__ __launch_bounds__(256) void init_alive(float* __restrict__ alive) {
  int i = blockIdx.x * 256 + threadIdx.x;
  if (i < NN) alive[i] = 1.0f;
}

// ---------------------------------------------------------------------------
// Build per-graph incoming-CSR (counting sort by dst). One block per graph.
// Output is written INTO the graph's own src-half of edge_index (dead after
// this kernel; harness restores d_in before every launch):
//   bytes [g*64KB, g*64KB+32KB) : src_sorted ushort[16384] (local src ids)
//   bytes [g*64KB+32KB, +2KB)   : rs ushort[1024] (exclusive start offsets)
__global__ __launch_bounds__(256) void csr_build(int* __restrict__ ei) {
  __shared__ unsigned int ed[EPG];   // packed src | dst<<10  (64 KB)
  __shared__ int cnt[NPG];
  __shared__ int scn[NPG];
  __shared__ int off[NPG];
  int g = blockIdx.x, t = threadIdx.x;
  const int* srcg = ei + (size_t)g * EPG;
  const int* dstg = ei + (size_t)NGPH * EPG + (size_t)g * EPG;
  for (int i = t; i < EPG; i += 256) {
    unsigned int s = (unsigned int)(srcg[i] - (g << 10));
    unsigned int d = (unsigned int)(dstg[i] - (g << 10));
    ed[i] = s | (d << 10);
  }
  for (int i = t; i < NPG; i += 256) cnt[i] = 0;
  __syncthreads();
  for (int i = t; i < EPG; i += 256) atomicAdd(&cnt[ed[i] >> 10], 1);
  __syncthreads();
  // inclusive Hillis-Steele scan over 1024 entries, double-buffered
  int* a = cnt; int* b = scn;
  for (int d = 1; d < NPG; d <<= 1) {
    for (int i = t; i < NPG; i += 256) b[i] = a[i] + (i >= d ? a[i - d] : 0);
    __syncthreads();
    int* tmp = a; a = b; b = tmp;
  }
  unsigned short* ssort = (unsigned short*)(ei + (size_t)g * EPG);
  unsigned short* rsout = ssort + EPG;     // byte offset +32KB
  for (int r = t; r < NPG; r += 256) {
    int ex = r ? a[r - 1] : 0;             // exclusive prefix
    rsout[r] = (unsigned short)ex;
    off[r] = ex;
  }
  __syncthreads();
  for (int i = t; i < EPG; i += 256) {
    unsigned int e = ed[i];
    int pos = atomicAdd(&off[e >> 10], 1);
    ssort[pos] = (unsigned short)(e & 1023u);
  }
}

// ---------------------------------------------------------------------------
// Mean aggregation via CSR gather, deg fused, writes MEAN directly.
// Block 256 = 8 rows x 32 lanes (float4 per lane -> 128 feats).
__global__ __launch_bounds__(256) void agg2_kernel(const float* __restrict__ X,
                                                   const int* __restrict__ ei,
                                                   const float* __restrict__ alive,
                                                   float* __restrict__ Mout) {
  int t = threadIdx.x;
  int row = blockIdx.x * 8 + (t >> 5);
  int lane = t & 31;
  int g = row >> 10, r = row & 1023;
  const unsigned short* ss  = (const unsigned short*)(ei + (size_t)g * EPG);
  const unsigned short* rsg = ss + EPG;
  int start = rsg[r];
  int end   = (r < 1023) ? (int)rsg[r + 1] : EPG;
  const float4* X4 = (const float4*)X;
  size_t gb4 = (size_t)(g << 10) * 32;     // float4 base of this graph
  float4 acc = make_float4(0.f, 0.f, 0.f, 0.f);
  float degf = 0.f;
  for (int base = start; base < end; base += 32) {
    int ec = end - base; if (ec > 32) ec = 32;
    int sl = 0; float av = 0.f;
    if (lane < ec) {
      sl = ss[base + lane];
      av = alive[(g << 10) + sl];
    }
    degf += av;
    for (int e = 0; e < ec; ++e) {
      int s = __shfl(sl, e, 32);           // broadcast within 32-lane group
      float4 v = X4[gb4 + (size_t)s * 32 + lane];
      acc.x += v.x; acc.y += v.y; acc.z += v.z; acc.w += v.w;
    }
  }
#pragma unroll
  for (int m = 1; m <= 16; m <<= 1) degf += __shfl_xor(degf, m, 32);
  float inv = 1.0f / fmaxf(degf, 1.0f);
  acc.x *= inv; acc.y *= inv; acc.z *= inv; acc.w *= inv;
  ((float4*)Mout)[(size_t)row * 32 + lane] = acc;
}

// ---------------------------------------------------------------------------
// Hout = relu( S @ Wl^T + X @ Wr^T + bl ); S already holds the mean.
// In-place safe on S (each block reads/writes only its own 128 rows).
__global__ __launch_bounds__(256) void gemm_kernel(const float* S,
                                                   const float* __restrict__ X,
                                                   const float* __restrict__ Wl,
                                                   const float* __restrict__ Wr,
                                                   const float* __restrict__ bl,
                                                   float* Hout) {
  __shared__ __align__(16) float ATm[16][HD];  // mean, transposed [k][row]
  __shared__ __align__(16) float ATx[16][HD];  // x,    transposed [k][row]
  __shared__ __align__(16) float WTl[16][HD];  // Wl,   transposed [k][col]
  __shared__ __align__(16) float WTr[16][HD];  // Wr,   transposed [k][col]
  int t  = threadIdx.x;
  int r0 = blockIdx.x * 128;
  int tc = t & 15, tr = t >> 4;       // col group (x8), row group (x8)
  int sr = t & 127, sq = t >> 7;      // staging: row/col index + half select
  float acc[8][8];
#pragma unroll
  for (int i = 0; i < 8; ++i)
#pragma unroll
    for (int j = 0; j < 8; ++j) acc[i][j] = 0.f;

  for (int c0 = 0; c0 < HD; c0 += 16) {
#pragma unroll
    for (int j = 0; j < 2; ++j) {
      int k = (sq * 2 + j) * 4;
      float4 vs = *(const float4*)&S[(size_t)(r0 + sr) * HD + c0 + k];
      ATm[k + 0][sr] = vs.x; ATm[k + 1][sr] = vs.y;
      ATm[k + 2][sr] = vs.z; ATm[k + 3][sr] = vs.w;
      float4 vx = *(const float4*)&X[(size_t)(r0 + sr) * HD + c0 + k];
      ATx[k + 0][sr] = vx.x; ATx[k + 1][sr] = vx.y;
      ATx[k + 2][sr] = vx.z; ATx[k + 3][sr] = vx.w;
    }
    {
      int kb = sq * 8;
      float4 w0 = *(const float4*)&Wl[sr * HD + c0 + kb];
      float4 w1 = *(const float4*)&Wl[sr * HD + c0 + kb + 4];
      WTl[kb + 0][sr] = w0.x; WTl[kb + 1][sr] = w0.y;
      WTl[kb + 2][sr] = w0.z; WTl[kb + 3][sr] = w0.w;
      WTl[kb + 4][sr] = w1.x; WTl[kb + 5][sr] = w1.y;
      WTl[kb + 6][sr] = w1.z; WTl[kb + 7][sr] = w1.w;
      float4 u0 = *(const float4*)&Wr[sr * HD + c0 + kb];
      float4 u1 = *(const float4*)&Wr[sr * HD + c0 + kb + 4];
      WTr[kb + 0][sr] = u0.x; WTr[kb + 1][sr] = u0.y;
      WTr[kb + 2][sr] = u0.z; WTr[kb + 3][sr] = u0.w;
      WTr[kb + 4][sr] = u1.x; WTr[kb + 5][sr] = u1.y;
      WTr[kb + 6][sr] = u1.z; WTr[kb + 7][sr] = u1.w;
    }
    __syncthreads();
#pragma unroll
    for (int k = 0; k < 16; ++k) {
      float am[8], ax[8], wl[8], wr[8];
      *(float4*)&am[0] = *(const float4*)&ATm[k][tr * 8];
      *(float4*)&am[4] = *(const float4*)&ATm[k][tr * 8 + 4];
      *(float4*)&ax[0] = *(const float4*)&ATx[k][tr * 8];
      *(float4*)&ax[4] = *(const float4*)&ATx[k][tr * 8 + 4];
      *(float4*)&wl[0] = *(const float4*)&WTl[k][tc * 8];
      *(float4*)&wl[4] = *(const float4*)&WTl[k][tc * 8 + 4];
      *(float4*)&wr[0] = *(const float4*)&WTr[k][tc * 8];
      *(float4*)&wr[4] = *(const float4*)&WTr[k][tc * 8 + 4];
#pragma unroll
      for (int i = 0; i < 8; ++i)
#pragma unroll
        for (int j = 0; j < 8; ++j)
          acc[i][j] += am[i] * wl[j] + ax[i] * wr[j];
    }
    __syncthreads();
  }
  float4 b0 = *(const float4*)&bl[tc * 8];
  float4 b1 = *(const float4*)&bl[tc * 8 + 4];
  float bv[8] = {b0.x, b0.y, b0.z, b0.w, b1.x, b1.y, b1.z, b1.w};
#pragma unroll
  for (int i = 0; i < 8; ++i) {
    size_t row = (size_t)(r0 + tr * 8 + i);
    float4 o0, o1;
    o0.x = fmaxf(acc[i][0] + bv[0], 0.f); o0.y = fmaxf(acc[i][1] + bv[1], 0.f);
    o0.z = fmaxf(acc[i][2] + bv[2], 0.f); o0.w = fmaxf(acc[i][3] + bv[3], 0.f);
    o1.x = fmaxf(acc[i][4] + bv[4], 0.f); o1.y = fmaxf(acc[i][5] + bv[5], 0.f);
    o1.z = fmaxf(acc[i][6] + bv[6], 0.f); o1.w = fmaxf(acc[i][7] + bv[7], 0.f);
    *(float4*)&Hout[row * HD + tc * 8]     = o0;
    *(float4*)&Hout[row * HD + tc * 8 + 4] = o1;
  }
}

// ---------------------------------------------------------------------------
// Per-graph: score = (H.wp)/||wp||, bitonic-sort masked scores, threshold at
// kth largest, gate kept rows by tanh(score), zero the rest. IN-PLACE on XH.
__global__ __launch_bounds__(256) void topk_kernel(float* XH,
                                                   float* __restrict__ alive,
                                                   const float* __restrict__ wp,
                                                   int kk) {
  __shared__ float wps[HD];
  __shared__ float sc[NPG];
  __shared__ float srt[NPG];
  __shared__ float shv[1];
  int g = blockIdx.x, t = threadIdx.x;
  if (t < HD) wps[t] = wp[t];
  __syncthreads();
  if (t == 0) {
    float ss = 0.f;
    for (int i = 0; i < HD; ++i) ss += wps[i] * wps[i];
    shv[0] = 1.0f / (sqrtf(ss) + 1e-16f);
  }
  __syncthreads();
  float inv = shv[0];
  size_t gbase = (size_t)g * NPG * HD;
#pragma unroll
  for (int q = 0; q < 4; ++q) {
    int n = t + q * 256;
    const float* row = &XH[gbase + (size_t)n * HD];
    float s = 0.f;
    for (int c = 0; c < HD; c += 4) {
      float4 h4 = *(const float4*)&row[c];
      s += h4.x * wps[c] + h4.y * wps[c + 1] + h4.z * wps[c + 2] + h4.w * wps[c + 3];
    }
    s *= inv;
    sc[n] = s;
    srt[n] = (alive[(g << 10) + n] > 0.5f) ? s : -3.402823466e38f;
  }
  __syncthreads();
  // bitonic ascending sort of srt[0..1023]
  for (int k2 = 2; k2 <= NPG; k2 <<= 1) {
    for (int j = k2 >> 1; j > 0; j >>= 1) {
#pragma unroll
      for (int q = 0; q < 4; ++q) {
        int i = t + q * 256;
        int l = i ^ j;
        if (l > i) {
          float a = srt[i], b = srt[l];
          if ((a > b) == ((i & k2) == 0)) { srt[i] = b; srt[l] = a; }
        }
      }
      __syncthreads();
    }
  }
  float thr = srt[NPG - kk];   // kth-largest alive score
#pragma unroll
  for (int q = 0; q < 4; ++q) {
    int n = t + q * 256;
    float s = sc[n];
    bool isal = alive[(g << 10) + n] > 0.5f;
    bool sel = isal && (s >= thr);
    float gt = sel ? tanhf(s) : 0.f;
    float* row = &XH[gbase + (size_t)n * HD];
    for (int c = 0; c < HD; c += 4) {
      float4 h4 = *(const float4*)&row[c];
      float4 o = make_float4(h4.x * gt, h4.y * gt, h4.z * gt, h4.w * gt);
      *(float4*)&row[c] = o;
    }
    alive[(g << 10) + n] = sel ? 1.f : 0.f;
  }
}

// ---------------------------------------------------------------------------
// global mean pool (divisor exactly K3), 2-layer MLP, log_softmax
__global__ __launch_bounds__(128) void final_kernel(const float* __restrict__ X,
                                                    const float* __restrict__ Wf1,
                                                    const float* __restrict__ bf1,
                                                    const float* __restrict__ Wf2,
                                                    const float* __restrict__ bf2,
                                                    float* __restrict__ out) {
  __shared__ float pl[HD];
  __shared__ float h1[64];
  __shared__ float lg[10];
  __shared__ float red[2];
  int g = blockIdx.x, t = threadIdx.x;
  size_t base = (size_t)g * NPG * HD;
  float s = 0.f;
  for (int r = 0; r < NPG; ++r) s += X[base + (size_t)r * HD + t];
  pl[t] = s / (float)KS3;
  __syncthreads();
  if (t < 64) {
    float h = bf1[t];
    for (int f = 0; f < HD; ++f) h += pl[f] * Wf1[t * HD + f];
    h1[t] = fmaxf(h, 0.f);
  }
  __syncthreads();
  if (t < 10) {
    float z = bf2[t];
    for (int j = 0; j < 64; ++j) z += h1[j] * Wf2[t * 64 + j];
    lg[t] = z;
  }
  __syncthreads();
  if (t == 0) {
    float m = lg[0];
    for (int c = 1; c < 10; ++c) m = fmaxf(m, lg[c]);
    float ssum = 0.f;
    for (int c = 0; c < 10; ++c) ssum += expf(lg[c] - m);
    red[0] = m; red[1] = logf(ssum);
  }
  __syncthreads();
  if (t < 10) out[g * 10 + t] = lg[t] - red[0] - red[1];
}

// ---------------------------------------------------------------------------
extern "C" void kernel_launch(void* const* d_in, const int* in_sizes, int n_in,
                              void* d_out, int out_size, void* d_ws, size_t ws_size,
                              hipStream_t stream) {
  const float* x  = (const float*)d_in[0];
  int* ei         = (int*)d_in[1];          // src half becomes CSR after csr_build
  const float* Wl[3]  = {(const float*)d_in[2], (const float*)d_in[6],  (const float*)d_in[10]};
  const float* blv[3] = {(const float*)d_in[3], (const float*)d_in[7],  (const float*)d_in[11]};
  const float* Wr[3]  = {(const float*)d_in[4], (const float*)d_in[8],  (const float*)d_in[12]};
  const float* wp[3]  = {(const float*)d_in[5], (const float*)d_in[9],  (const float*)d_in[13]};
  const float* Wf1 = (const float*)d_in[14];
  const float* bf1 = (const float*)d_in[15];
  const float* Wf2 = (const float*)d_in[16];
  const float* bf2 = (const float*)d_in[17];
  float* out = (float*)d_out;

  // workspace: bufA (64MB) | bufB (64MB) | alive (512KB)
  float* bufA  = (float*)d_ws;
  float* bufB  = bufA + (size_t)NN * HD;
  float* alive = bufB + (size_t)NN * HD;

  init_alive<<<NN / 256, 256, 0, stream>>>(alive);
  csr_build<<<NGPH, 256, 0, stream>>>(ei);

  // L1: x -> mean(bufA) -> gemm in-place bufA -> topk in-place bufA
  agg2_kernel<<<NN / 8, 256, 0, stream>>>(x, ei, alive, bufA);
  gemm_kernel<<<NN / 128, 256, 0, stream>>>(bufA, x, Wl[0], Wr[0], blv[0], bufA);
  topk_kernel<<<NGPH, 256, 0, stream>>>(bufA, alive, wp[0], KS1);
  // L2: bufA -> mean(bufB) -> gemm in-place bufB -> topk in-place bufB
  agg2_kernel<<<NN / 8, 256, 0, stream>>>(bufA, ei, alive, bufB);
  gemm_kernel<<<NN / 128, 256, 0, stream>>>(bufB, bufA, Wl[1], Wr[1], blv[1], bufB);
  topk_kernel<<<NGPH, 256, 0, stream>>>(bufB, alive, wp[1], KS2);
  // L3: bufB -> mean(bufA) -> gemm in-place bufA -> topk in-place bufA
  agg2_kernel<<<NN / 8, 256, 0, stream>>>(bufB, ei, alive, bufA);
  gemm_kernel<<<NN / 128, 256, 0, stream>>>(bufA, bufB, Wl[2], Wr[2], blv[2], bufA);
  topk_kernel<<<NGPH, 256, 0, stream>>>(bufA, alive, wp[2], KS3);

  final_kernel<<<NGPH, 128, 0, stream>>>(bufA, Wf1, bf1, Wf2, bf2, out);
}

// Round 4
// 822.739 us; speedup vs baseline: 6.3520x; 1.7115x over previous
//
#include <hip/hip_runtime.h>

// Problem constants (match reference)
constexpr int NGPH = 128;            // graphs per batch
constexpr int NPG  = 1024;           // nodes per graph
constexpr int NN   = NGPH * NPG;     // 131072 nodes
constexpr int HD   = 128;            // feature width (FIN == H == 128)
constexpr int EPG  = 16384;          // edges per graph (E // B), contiguous per graph
constexpr int KS1 = 820, KS2 = 656, KS3 = 525;

typedef _Float16 half4v __attribute__((ext_vector_type(4)));
typedef _Float16 half8v __attribute__((ext_vector_type(8)));
typedef float f32x4 __attribute__((ext_vector_type(4)));

// ---------------------------------------------------------------------------
__global__ __launch_bounds__(256) void init_alive(float* __restrict__ alive) {
  int i = blockIdx.x * 256 + threadIdx.x;
  if (i < NN) alive[i] = 1.0f;
}

// ---------------------------------------------------------------------------
// Convert all 3 layers' [Wl|Wr] (fp32) to fp16 hi/lo planes:
// Wc[layer][plane][n][k], plane 0 = hi, 1 = lo; k<128 -> Wl, k>=128 -> Wr.
__global__ __launch_bounds__(256) void wconv(const float* __restrict__ Wl0, const float* __restrict__ Wr0,
                                             const float* __restrict__ Wl1, const float* __restrict__ Wr1,
                                             const float* __restrict__ Wl2, const float* __restrict__ Wr2,
                                             _Float16* __restrict__ Wc) {
  int tid = blockIdx.x * 256 + threadIdx.x;      // 3*32768
  int layer = tid >> 15;
  int idx = tid & 32767;
  int n = idx >> 8, k = idx & 255;
  const float* Wlp = layer == 0 ? Wl0 : layer == 1 ? Wl1 : Wl2;
  const float* Wrp = layer == 0 ? Wr0 : layer == 1 ? Wr1 : Wr2;
  float v = (k < 128) ? Wlp[n * 128 + k] : Wrp[n * 128 + k - 128];
  _Float16 h = (_Float16)v;
  _Float16 l = (_Float16)(v - (float)h);
  size_t base = (size_t)layer * 65536;
  Wc[base + (size_t)n * 256 + k] = h;
  Wc[base + 32768 + (size_t)n * 256 + k] = l;
}

// ---------------------------------------------------------------------------
// Build per-graph incoming-CSR (counting sort by dst). One block per graph.
// Output overwrites the graph's own src-half of edge_index (dead afterwards;
// harness restores d_in before every launch):
//   [g*64KB, +32KB) : src_sorted ushort[16384];  [+32KB, +2KB) : rs ushort[1024]
__global__ __launch_bounds__(256) void csr_build(int* __restrict__ ei) {
  __shared__ unsigned int ed[EPG];   // packed src | dst<<10  (64 KB)
  __shared__ int cnt[NPG];
  __shared__ int scn[NPG];
  __shared__ int off[NPG];
  int g = blockIdx.x, t = threadIdx.x;
  const int* srcg = ei + (size_t)g * EPG;
  const int* dstg = ei + (size_t)NGPH * EPG + (size_t)g * EPG;
  for (int i = t; i < EPG; i += 256) {
    unsigned int s = (unsigned int)(srcg[i] - (g << 10));
    unsigned int d = (unsigned int)(dstg[i] - (g << 10));
    ed[i] = s | (d << 10);
  }
  for (int i = t; i < NPG; i += 256) cnt[i] = 0;
  __syncthreads();
  for (int i = t; i < EPG; i += 256) atomicAdd(&cnt[ed[i] >> 10], 1);
  __syncthreads();
  int* a = cnt; int* b = scn;
  for (int d = 1; d < NPG; d <<= 1) {
    for (int i = t; i < NPG; i += 256) b[i] = a[i] + (i >= d ? a[i - d] : 0);
    __syncthreads();
    int* tmp = a; a = b; b = tmp;
  }
  unsigned short* ssort = (unsigned short*)(ei + (size_t)g * EPG);
  unsigned short* rsout = ssort + EPG;
  for (int r = t; r < NPG; r += 256) {
    int ex = r ? a[r - 1] : 0;
    rsout[r] = (unsigned short)ex;
    off[r] = ex;
  }
  __syncthreads();
  for (int i = t; i < EPG; i += 256) {
    unsigned int e = ed[i];
    int pos = atomicAdd(&off[e >> 10], 1);
    ssort[pos] = (unsigned short)(e & 1023u);
  }
}

// ---------------------------------------------------------------------------
// Mean aggregation via CSR gather, deg fused, writes MEAN directly.
__global__ __launch_bounds__(256) void agg2_kernel(const float* __restrict__ X,
                                                   const int* __restrict__ ei,
                                                   const float* __restrict__ alive,
                                                   float* __restrict__ Mout) {
  int t = threadIdx.x;
  int row = blockIdx.x * 8 + (t >> 5);
  int lane = t & 31;
  int g = row >> 10, r = row & 1023;
  const unsigned short* ss  = (const unsigned short*)(ei + (size_t)g * EPG);
  const unsigned short* rsg = ss + EPG;
  int start = rsg[r];
  int end   = (r < 1023) ? (int)rsg[r + 1] : EPG;
  const float4* X4 = (const float4*)X;
  size_t gb4 = (size_t)(g << 10) * 32;
  float4 acc = make_float4(0.f, 0.f, 0.f, 0.f);
  float degf = 0.f;
  for (int base = start; base < end; base += 32) {
    int ec = end - base; if (ec > 32) ec = 32;
    int sl = 0; float av = 0.f;
    if (lane < ec) {
      sl = ss[base + lane];
      av = alive[(g << 10) + sl];
    }
    degf += av;
    for (int e = 0; e < ec; ++e) {
      int s = __shfl(sl, e, 32);
      float4 v = X4[gb4 + (size_t)s * 32 + lane];
      acc.x += v.x; acc.y += v.y; acc.z += v.z; acc.w += v.w;
    }
  }
#pragma unroll
  for (int m = 1; m <= 16; m <<= 1) degf += __shfl_xor(degf, m, 32);
  float inv = 1.0f / fmaxf(degf, 1.0f);
  acc.x *= inv; acc.y *= inv; acc.z *= inv; acc.w *= inv;
  ((float4*)Mout)[(size_t)row * 32 + lane] = acc;
}

// ---------------------------------------------------------------------------
// Hout = relu( S @ Wl^T + X @ Wr^T + bias ) via fp16-split MFMA.
// A = [S | X] (K=256). 128x128 tile/block, 4 waves in 2x2, each wave 64x64
// as 4x4 grid of 16x16x32 f16 MFMAs, 3 products (hh, hl, lh) per pair.
// In-place safe on S (block reads/writes only its own 128 rows; all loads
// precede all stores).
constexpr int LDA = 40;   // fp16 elements per LDS row (32 + 8 pad)
__global__ __launch_bounds__(256) void gemm_mfma(const float* S,
                                                 const float* __restrict__ X,
                                                 const _Float16* __restrict__ Wc,
                                                 const float* __restrict__ bb,
                                                 float* Hout) {
  __shared__ _Float16 Ah[128 * LDA];
  __shared__ _Float16 Al[128 * LDA];
  __shared__ _Float16 Bh[128 * LDA];
  __shared__ _Float16 Bl[128 * LDA];
  int t = threadIdx.x;
  int r0 = blockIdx.x * 128;
  int lane = t & 63, wid = t >> 6;
  int wm = wid & 1, wn = wid >> 1;
  int quad = lane >> 4, mr = lane & 15;
  const _Float16* WH = Wc;
  const _Float16* WL = Wc + 32768;

  f32x4 acc[4][4];
#pragma unroll
  for (int i = 0; i < 4; ++i)
#pragma unroll
    for (int j = 0; j < 4; ++j) acc[i][j] = (f32x4){0.f, 0.f, 0.f, 0.f};

  for (int ks = 0; ks < 256; ks += 32) {
    // ---- stage A (fp32 -> hi/lo fp16), 128 rows x 32 k
    const float* Asrc = (ks < 128) ? (S + (size_t)r0 * HD + ks)
                                   : (X + (size_t)r0 * HD + (ks - 128));
#pragma unroll
    for (int i = 0; i < 4; ++i) {
      int f = t + i * 256;           // float4 slot 0..1023
      int row = f >> 3;
      int kq = (f & 7) * 4;
      float4 v = *(const float4*)&Asrc[(size_t)row * HD + kq];
      half4v h, l;
      h.x = (_Float16)v.x; h.y = (_Float16)v.y; h.z = (_Float16)v.z; h.w = (_Float16)v.w;
      l.x = (_Float16)(v.x - (float)h.x); l.y = (_Float16)(v.y - (float)h.y);
      l.z = (_Float16)(v.z - (float)h.z); l.w = (_Float16)(v.w - (float)h.w);
      *(half4v*)&Ah[row * LDA + kq] = h;
      *(half4v*)&Al[row * LDA + kq] = l;
    }
    // ---- stage W (pre-converted fp16), 128 n x 32 k
#pragma unroll
    for (int i = 0; i < 2; ++i) {
      int f = t + i * 256;           // half8 slot 0..511
      int row = f >> 2;
      int kq = (f & 3) * 8;
      *(half8v*)&Bh[row * LDA + kq] = *(const half8v*)&WH[(size_t)row * 256 + ks + kq];
      *(half8v*)&Bl[row * LDA + kq] = *(const half8v*)&WL[(size_t)row * 256 + ks + kq];
    }
    __syncthreads();
    // ---- fragments + MFMA
    half8v af[4], alf[4], bf[4], blf[4];
#pragma unroll
    for (int i = 0; i < 4; ++i) {
      int rowA = (wm * 64 + i * 16 + mr) * LDA + quad * 8;
      af[i]  = *(const half8v*)&Ah[rowA];
      alf[i] = *(const half8v*)&Al[rowA];
    }
#pragma unroll
    for (int j = 0; j < 4; ++j) {
      int rowW = (wn * 64 + j * 16 + mr) * LDA + quad * 8;
      bf[j]  = *(const half8v*)&Bh[rowW];
      blf[j] = *(const half8v*)&Bl[rowW];
    }
#pragma unroll
    for (int i = 0; i < 4; ++i)
#pragma unroll
      for (int j = 0; j < 4; ++j) {
        acc[i][j] = __builtin_amdgcn_mfma_f32_16x16x32_f16(af[i],  bf[j],  acc[i][j], 0, 0, 0);
        acc[i][j] = __builtin_amdgcn_mfma_f32_16x16x32_f16(af[i],  blf[j], acc[i][j], 0, 0, 0);
        acc[i][j] = __builtin_amdgcn_mfma_f32_16x16x32_f16(alf[i], bf[j],  acc[i][j], 0, 0, 0);
      }
    __syncthreads();
  }
  // ---- epilogue: bias + relu, C/D layout col=lane&15, row=quad*4+reg
#pragma unroll
  for (int j = 0; j < 4; ++j) {
    int col = wn * 64 + j * 16 + mr;
    float bias = bb[col];
#pragma unroll
    for (int i = 0; i < 4; ++i) {
      int rowg = r0 + wm * 64 + i * 16 + quad * 4;
#pragma unroll
      for (int r = 0; r < 4; ++r)
        Hout[(size_t)(rowg + r) * HD + col] = fmaxf(acc[i][j][r] + bias, 0.f);
    }
  }
}

// ---------------------------------------------------------------------------
// Per-graph: score = (H.wp)/||wp||, bitonic-sort masked scores, threshold at
// kth largest, gate kept rows by tanh(score), zero the rest. IN-PLACE on XH.
__global__ __launch_bounds__(256) void topk_kernel(float* XH,
                                                   float* __restrict__ alive,
                                                   const float* __restrict__ wp,
                                                   int kk) {
  __shared__ float wps[HD];
  __shared__ float sc[NPG];
  __shared__ float srt[NPG];
  __shared__ float shv[1];
  int g = blockIdx.x, t = threadIdx.x;
  if (t < HD) wps[t] = wp[t];
  __syncthreads();
  if (t == 0) {
    float ss = 0.f;
    for (int i = 0; i < HD; ++i) ss += wps[i] * wps[i];
    shv[0] = 1.0f / (sqrtf(ss) + 1e-16f);
  }
  __syncthreads();
  float inv = shv[0];
  size_t gbase = (size_t)g * NPG * HD;
#pragma unroll
  for (int q = 0; q < 4; ++q) {
    int n = t + q * 256;
    const float* row = &XH[gbase + (size_t)n * HD];
    float s = 0.f;
    for (int c = 0; c < HD; c += 4) {
      float4 h4 = *(const float4*)&row[c];
      s += h4.x * wps[c] + h4.y * wps[c + 1] + h4.z * wps[c + 2] + h4.w * wps[c + 3];
    }
    s *= inv;
    sc[n] = s;
    srt[n] = (alive[(g << 10) + n] > 0.5f) ? s : -3.402823466e38f;
  }
  __syncthreads();
  for (int k2 = 2; k2 <= NPG; k2 <<= 1) {
    for (int j = k2 >> 1; j > 0; j >>= 1) {
#pragma unroll
      for (int q = 0; q < 4; ++q) {
        int i = t + q * 256;
        int l = i ^ j;
        if (l > i) {
          float a = srt[i], b = srt[l];
          if ((a > b) == ((i & k2) == 0)) { srt[i] = b; srt[l] = a; }
        }
      }
      __syncthreads();
    }
  }
  float thr = srt[NPG - kk];
#pragma unroll
  for (int q = 0; q < 4; ++q) {
    int n = t + q * 256;
    float s = sc[n];
    bool isal = alive[(g << 10) + n] > 0.5f;
    bool sel = isal && (s >= thr);
    float gt = sel ? tanhf(s) : 0.f;
    float* row = &XH[gbase + (size_t)n * HD];
    for (int c = 0; c < HD; c += 4) {
      float4 h4 = *(const float4*)&row[c];
      float4 o = make_float4(h4.x * gt, h4.y * gt, h4.z * gt, h4.w * gt);
      *(float4*)&row[c] = o;
    }
    alive[(g << 10) + n] = sel ? 1.f : 0.f;
  }
}

// ---------------------------------------------------------------------------
// global mean pool (divisor exactly K3), 2-layer MLP, log_softmax
__global__ __launch_bounds__(128) void final_kernel(const float* __restrict__ X,
                                                    const float* __restrict__ Wf1,
                                                    const float* __restrict__ bf1,
                                                    const float* __restrict__ Wf2,
                                                    const float* __restrict__ bf2,
                                                    float* __restrict__ out) {
  __shared__ float pl[HD];
  __shared__ float h1[64];
  __shared__ float lg[10];
  __shared__ float red[2];
  int g = blockIdx.x, t = threadIdx.x;
  size_t base = (size_t)g * NPG * HD;
  float s = 0.f;
  for (int r = 0; r < NPG; ++r) s += X[base + (size_t)r * HD + t];
  pl[t] = s / (float)KS3;
  __syncthreads();
  if (t < 64) {
    float h = bf1[t];
    for (int f = 0; f < HD; ++f) h += pl[f] * Wf1[t * HD + f];
    h1[t] = fmaxf(h, 0.f);
  }
  __syncthreads();
  if (t < 10) {
    float z = bf2[t];
    for (int j = 0; j < 64; ++j) z += h1[j] * Wf2[t * 64 + j];
    lg[t] = z;
  }
  __syncthreads();
  if (t == 0) {
    float m = lg[0];
    for (int c = 1; c < 10; ++c) m = fmaxf(m, lg[c]);
    float ssum = 0.f;
    for (int c = 0; c < 10; ++c) ssum += expf(lg[c] - m);
    red[0] = m; red[1] = logf(ssum);
  }
  __syncthreads();
  if (t < 10) out[g * 10 + t] = lg[t] - red[0] - red[1];
}

// ---------------------------------------------------------------------------
extern "C" void kernel_launch(void* const* d_in, const int* in_sizes, int n_in,
                              void* d_out, int out_size, void* d_ws, size_t ws_size,
                              hipStream_t stream) {
  const float* x  = (const float*)d_in[0];
  int* ei         = (int*)d_in[1];          // src half becomes CSR after csr_build
  const float* Wl[3]  = {(const float*)d_in[2], (const float*)d_in[6],  (const float*)d_in[10]};
  const float* blv[3] = {(const float*)d_in[3], (const float*)d_in[7],  (const float*)d_in[11]};
  const float* Wr[3]  = {(const float*)d_in[4], (const float*)d_in[8],  (const float*)d_in[12]};
  const float* wp[3]  = {(const float*)d_in[5], (const float*)d_in[9],  (const float*)d_in[13]};
  const float* Wf1 = (const float*)d_in[14];
  const float* bf1 = (const float*)d_in[15];
  const float* Wf2 = (const float*)d_in[16];
  const float* bf2 = (const float*)d_in[17];
  float* out = (float*)d_out;

  // workspace: bufA (64MB) | bufB (64MB) | alive (512KB) | Wcvt (384KB)
  float* bufA  = (float*)d_ws;
  float* bufB  = bufA + (size_t)NN * HD;
  float* alive = bufB + (size_t)NN * HD;
  _Float16* Wcvt = (_Float16*)(alive + NN);

  init_alive<<<NN / 256, 256, 0, stream>>>(alive);
  wconv<<<384, 256, 0, stream>>>(Wl[0], Wr[0], Wl[1], Wr[1], Wl[2], Wr[2], Wcvt);
  csr_build<<<NGPH, 256, 0, stream>>>(ei);

  // L1: x -> mean(bufA) -> gemm in-place bufA -> topk in-place bufA
  agg2_kernel<<<NN / 8, 256, 0, stream>>>(x, ei, alive, bufA);
  gemm_mfma<<<NN / 128, 256, 0, stream>>>(bufA, x, Wcvt, blv[0], bufA);
  topk_kernel<<<NGPH, 256, 0, stream>>>(bufA, alive, wp[0], KS1);
  // L2
  agg2_kernel<<<NN / 8, 256, 0, stream>>>(bufA, ei, alive, bufB);
  gemm_mfma<<<NN / 128, 256, 0, stream>>>(bufB, bufA, Wcvt + 65536, blv[1], bufB);
  topk_kernel<<<NGPH, 256, 0, stream>>>(bufB, alive, wp[1], KS2);
  // L3
  agg2_kernel<<<NN / 8, 256, 0, stream>>>(bufB, ei, alive, bufA);
  gemm_mfma<<<NN / 128, 256, 0, stream>>>(bufA, bufB, Wcvt + 131072, blv[2], bufA);
  topk_kernel<<<NGPH, 256, 0, stream>>>(bufA, alive, wp[2], KS3);

  final_kernel<<<NGPH, 128, 0, stream>>>(bufA, Wf1, bf1, Wf2, bf2, out);
}

// Round 5
// 562.566 us; speedup vs baseline: 9.2897x; 1.4625x over previous
//
#include <hip/hip_runtime.h>

// Problem constants (match reference)
constexpr int NGPH = 128;            // graphs per batch
constexpr int NPG  = 1024;           // nodes per graph
constexpr int NN   = NGPH * NPG;     // 131072 nodes
constexpr int HD   = 128;            // feature width (FIN == H == 128)
constexpr int EPG  = 16384;          // edges per graph (E // B), contiguous per graph
constexpr int KS1 = 820, KS2 = 656, KS3 = 525;

typedef _Float16 half4v __attribute__((ext_vector_type(4)));
typedef _Float16 half8v __attribute__((ext_vector_type(8)));
typedef float f32x4 __attribute__((ext_vector_type(4)));

// ---------------------------------------------------------------------------
// gate = 1.0 for all nodes (ws is poisoned 0xAA before each call).
// gate[i] != 0  <=>  node alive. (alive gates are tanh(s), s!=0 a.s.)
__global__ __launch_bounds__(256) void init_gate(float* __restrict__ gate) {
  int i = blockIdx.x * 256 + threadIdx.x;
  if (i < NN) gate[i] = 1.0f;
}

// ---------------------------------------------------------------------------
// Build per-graph incoming-CSR (counting sort by dst). One block per graph.
// Output overwrites the graph's own src-half of edge_index (dead afterwards;
// harness restores d_in before every launch):
//   [g*64KB, +32KB) : src_sorted ushort[16384];  [+32KB, +2KB) : rs ushort[1024]
__global__ __launch_bounds__(512) void csr_build(int* __restrict__ ei) {
  __shared__ unsigned int ed[EPG];   // packed src | dst<<10  (64 KB)
  __shared__ int cnt[NPG];
  __shared__ int scn[NPG];
  __shared__ int off[NPG];
  int g = blockIdx.x, t = threadIdx.x;
  const int* srcg = ei + (size_t)g * EPG;
  const int* dstg = ei + (size_t)NGPH * EPG + (size_t)g * EPG;
  for (int i = t; i < EPG; i += 512) {
    unsigned int s = (unsigned int)(srcg[i] - (g << 10));
    unsigned int d = (unsigned int)(dstg[i] - (g << 10));
    ed[i] = s | (d << 10);
  }
  for (int i = t; i < NPG; i += 512) cnt[i] = 0;
  __syncthreads();
  for (int i = t; i < EPG; i += 512) atomicAdd(&cnt[ed[i] >> 10], 1);
  __syncthreads();
  int* a = cnt; int* b = scn;
  for (int d = 1; d < NPG; d <<= 1) {
    for (int i = t; i < NPG; i += 512) b[i] = a[i] + (i >= d ? a[i - d] : 0);
    __syncthreads();
    int* tmp = a; a = b; b = tmp;
  }
  unsigned short* ssort = (unsigned short*)(ei + (size_t)g * EPG);
  unsigned short* rsout = ssort + EPG;
  for (int r = t; r < NPG; r += 512) {
    int ex = r ? a[r - 1] : 0;
    rsout[r] = (unsigned short)ex;
    off[r] = ex;
  }
  __syncthreads();
  for (int i = t; i < EPG; i += 512) {
    unsigned int e = ed[i];
    int pos = atomicAdd(&off[e >> 10], 1);
    ssort[pos] = (unsigned short)(e & 1023u);
  }
}

// ---------------------------------------------------------------------------
// Mean aggregation via CSR gather. Applies gate[src] on the fly (X holds
// UNGATED features), deg = #alive in-neighbors, writes MEAN directly.
// XCD swizzle: xcd = blockIdx&7; each XCD streams its 16 graphs one at a
// time so the 512 KB graph slice stays L2-resident.
__global__ __launch_bounds__(256) void agg2_kernel(const float* __restrict__ X,
                                                   const int* __restrict__ ei,
                                                   const float* __restrict__ gate,
                                                   float* __restrict__ Mout) {
  int t = threadIdx.x;
  int xcd = blockIdx.x & 7, q = blockIdx.x >> 3;
  int g = ((q >> 7) << 3) + xcd;
  int r = (q & 127) * 8 + (t >> 5);
  int lane = t & 31;
  const unsigned short* ss  = (const unsigned short*)(ei + (size_t)g * EPG);
  const unsigned short* rsg = ss + EPG;
  int start = rsg[r];
  int end   = (r < 1023) ? (int)rsg[r + 1] : EPG;
  const float4* X4 = (const float4*)X;
  size_t gb4 = (size_t)(g << 10) * 32;
  float4 acc = make_float4(0.f, 0.f, 0.f, 0.f);
  float degf = 0.f;
  for (int base = start; base < end; base += 32) {
    int ec = end - base; if (ec > 32) ec = 32;
    int sl = 0; float gv = 0.f;
    if (lane < ec) {
      sl = ss[base + lane];
      gv = gate[(g << 10) + sl];
    }
    degf += (gv != 0.f) ? 1.f : 0.f;
    int e = 0;
    for (; e + 4 <= ec; e += 4) {
      int s0 = __shfl(sl, e, 32),     s1 = __shfl(sl, e + 1, 32);
      int s2 = __shfl(sl, e + 2, 32), s3 = __shfl(sl, e + 3, 32);
      float g0 = __shfl(gv, e, 32),     g1 = __shfl(gv, e + 1, 32);
      float g2 = __shfl(gv, e + 2, 32), g3 = __shfl(gv, e + 3, 32);
      float4 v0 = X4[gb4 + (size_t)s0 * 32 + lane];
      float4 v1 = X4[gb4 + (size_t)s1 * 32 + lane];
      float4 v2 = X4[gb4 + (size_t)s2 * 32 + lane];
      float4 v3 = X4[gb4 + (size_t)s3 * 32 + lane];
      acc.x += v0.x * g0 + v1.x * g1 + v2.x * g2 + v3.x * g3;
      acc.y += v0.y * g0 + v1.y * g1 + v2.y * g2 + v3.y * g3;
      acc.z += v0.z * g0 + v1.z * g1 + v2.z * g2 + v3.z * g3;
      acc.w += v0.w * g0 + v1.w * g1 + v2.w * g2 + v3.w * g3;
    }
    for (; e < ec; ++e) {
      int s0 = __shfl(sl, e, 32);
      float g0 = __shfl(gv, e, 32);
      float4 v0 = X4[gb4 + (size_t)s0 * 32 + lane];
      acc.x += v0.x * g0; acc.y += v0.y * g0;
      acc.z += v0.z * g0; acc.w += v0.w * g0;
    }
  }
#pragma unroll
  for (int m = 1; m <= 16; m <<= 1) degf += __shfl_xor(degf, m, 32);
  float inv = 1.0f / fmaxf(degf, 1.0f);
  acc.x *= inv; acc.y *= inv; acc.z *= inv; acc.w *= inv;
  ((float4*)Mout)[(size_t)((g << 10) + r) * 32 + lane] = acc;
}

// ---------------------------------------------------------------------------
// Hout = relu( S @ Wl^T + (X*gate) @ Wr^T + bias ) via fp16-split MFMA, and
// score[node] = Hout[node,:] . wp  (raw, unnormalized) fused in the epilogue.
// A = [S | X*gate] (K=256). W converted fp32->hi/lo fp16 during staging
// (same global bytes as fp16 planes). 128x128 tile/block, 4 waves 2x2,
// each wave 64x64 as 4x4 grid of 16x16x32 f16 MFMAs, products hh+hl+lh.
// In-place safe on S (block-local rows; all loads precede all stores).
constexpr int LDA = 40;   // fp16 elements per LDS row (32 + 8 pad)
__global__ __launch_bounds__(256) void gemm_mfma(const float* S,
                                                 const float* __restrict__ X,
                                                 const float* __restrict__ Wl,
                                                 const float* __restrict__ Wr,
                                                 const float* __restrict__ bb,
                                                 const float* __restrict__ wp,
                                                 const float* __restrict__ gate,
                                                 float* Hout,
                                                 float* __restrict__ score) {
  __shared__ _Float16 Ah[128 * LDA];
  __shared__ _Float16 Al[128 * LDA];
  __shared__ _Float16 Bh[128 * LDA];
  __shared__ _Float16 Bl[128 * LDA];
  __shared__ float sc_s[128];
  int t = threadIdx.x;
  int r0 = blockIdx.x * 128;
  int lane = t & 63, wid = t >> 6;
  int wm = wid & 1, wn = wid >> 1;
  int quad = lane >> 4, mr = lane & 15;

  f32x4 acc[4][4];
#pragma unroll
  for (int i = 0; i < 4; ++i)
#pragma unroll
    for (int j = 0; j < 4; ++j) acc[i][j] = (f32x4){0.f, 0.f, 0.f, 0.f};

  for (int ks = 0; ks < 256; ks += 32) {
    bool isS = (ks < 128);
    // ---- stage A (fp32 -> hi/lo fp16), 128 rows x 32 k; X-term gated
    const float* Asrc = isS ? (S + (size_t)r0 * HD + ks)
                            : (X + (size_t)r0 * HD + (ks - 128));
#pragma unroll
    for (int i = 0; i < 4; ++i) {
      int f = t + i * 256;           // float4 slot 0..1023
      int row = f >> 3;
      int kq = (f & 7) * 4;
      float4 v = *(const float4*)&Asrc[(size_t)row * HD + kq];
      if (!isS) {
        float gv = gate[r0 + row];
        v.x *= gv; v.y *= gv; v.z *= gv; v.w *= gv;
      }
      half4v h, l;
      h.x = (_Float16)v.x; h.y = (_Float16)v.y; h.z = (_Float16)v.z; h.w = (_Float16)v.w;
      l.x = (_Float16)(v.x - (float)h.x); l.y = (_Float16)(v.y - (float)h.y);
      l.z = (_Float16)(v.z - (float)h.z); l.w = (_Float16)(v.w - (float)h.w);
      *(half4v*)&Ah[row * LDA + kq] = h;
      *(half4v*)&Al[row * LDA + kq] = l;
    }
    // ---- stage W (fp32 -> hi/lo fp16), 128 n x 32 k
    const float* Wsrc = isS ? (Wl + ks) : (Wr + (ks - 128));
#pragma unroll
    for (int i = 0; i < 4; ++i) {
      int f = t + i * 256;
      int row = f >> 3;
      int kq = (f & 7) * 4;
      float4 v = *(const float4*)&Wsrc[(size_t)row * HD + kq];
      half4v h, l;
      h.x = (_Float16)v.x; h.y = (_Float16)v.y; h.z = (_Float16)v.z; h.w = (_Float16)v.w;
      l.x = (_Float16)(v.x - (float)h.x); l.y = (_Float16)(v.y - (float)h.y);
      l.z = (_Float16)(v.z - (float)h.z); l.w = (_Float16)(v.w - (float)h.w);
      *(half4v*)&Bh[row * LDA + kq] = h;
      *(half4v*)&Bl[row * LDA + kq] = l;
    }
    __syncthreads();
    // ---- fragments + MFMA
    half8v af[4], alf[4], bf[4], blf[4];
#pragma unroll
    for (int i = 0; i < 4; ++i) {
      int rowA = (wm * 64 + i * 16 + mr) * LDA + quad * 8;
      af[i]  = *(const half8v*)&Ah[rowA];
      alf[i] = *(const half8v*)&Al[rowA];
    }
#pragma unroll
    for (int j = 0; j < 4; ++j) {
      int rowW = (wn * 64 + j * 16 + mr) * LDA + quad * 8;
      bf[j]  = *(const half8v*)&Bh[rowW];
      blf[j] = *(const half8v*)&Bl[rowW];
    }
#pragma unroll
    for (int i = 0; i < 4; ++i)
#pragma unroll
      for (int j = 0; j < 4; ++j) {
        acc[i][j] = __builtin_amdgcn_mfma_f32_16x16x32_f16(af[i],  bf[j],  acc[i][j], 0, 0, 0);
        acc[i][j] = __builtin_amdgcn_mfma_f32_16x16x32_f16(af[i],  blf[j], acc[i][j], 0, 0, 0);
        acc[i][j] = __builtin_amdgcn_mfma_f32_16x16x32_f16(alf[i], bf[j],  acc[i][j], 0, 0, 0);
      }
    __syncthreads();
  }
  // ---- epilogue: bias + relu + H store + fused score = relu(H).wp
  if (t < 128) sc_s[t] = 0.f;
  __syncthreads();
  float p[4][4];   // [i][r] partial row-dot over this wave's 64 cols
#pragma unroll
  for (int i = 0; i < 4; ++i)
#pragma unroll
    for (int r = 0; r < 4; ++r) p[i][r] = 0.f;
#pragma unroll
  for (int j = 0; j < 4; ++j) {
    int col = wn * 64 + j * 16 + mr;
    float bias = bb[col];
    float wv = wp[col];
#pragma unroll
    for (int i = 0; i < 4; ++i) {
      int rowg = r0 + wm * 64 + i * 16 + quad * 4;
#pragma unroll
      for (int r = 0; r < 4; ++r) {
        float ho = fmaxf(acc[i][j][r] + bias, 0.f);
        Hout[(size_t)(rowg + r) * HD + col] = ho;
        p[i][r] += ho * wv;
      }
    }
  }
  // reduce across the 16 lanes (mr) that share a row
#pragma unroll
  for (int i = 0; i < 4; ++i)
#pragma unroll
    for (int r = 0; r < 4; ++r) {
#pragma unroll
      for (int m = 1; m <= 8; m <<= 1) p[i][r] += __shfl_xor(p[i][r], m, 16);
      if (mr == 0) atomicAdd(&sc_s[wm * 64 + i * 16 + quad * 4 + r], p[i][r]);
    }
  __syncthreads();
  if (t < 128) score[r0 + t] = sc_s[t];
}

// ---------------------------------------------------------------------------
// Per-graph: normalize scores, bitonic-sort alive-masked scores, threshold at
// kth largest, write gate = tanh(s) for kept nodes else 0. No feature traffic.
__global__ __launch_bounds__(256) void topk_kernel(const float* __restrict__ score,
                                                   float* __restrict__ gate,
                                                   const float* __restrict__ wp,
                                                   int kk) {
  __shared__ float sc[NPG];
  __shared__ float srt[NPG];
  __shared__ float shv[1];
  int g = blockIdx.x, t = threadIdx.x;
  if (t == 0) {
    float ss = 0.f;
    for (int i = 0; i < HD; ++i) ss += wp[i] * wp[i];
    shv[0] = 1.0f / (sqrtf(ss) + 1e-16f);
  }
  __syncthreads();
  float inv = shv[0];
#pragma unroll
  for (int q = 0; q < 4; ++q) {
    int n = t + q * 256;
    float s = score[(g << 10) + n] * inv;
    sc[n] = s;
    srt[n] = (gate[(g << 10) + n] != 0.f) ? s : -3.402823466e38f;
  }
  __syncthreads();
  for (int k2 = 2; k2 <= NPG; k2 <<= 1) {
    for (int j = k2 >> 1; j > 0; j >>= 1) {
#pragma unroll
      for (int q = 0; q < 4; ++q) {
        int i = t + q * 256;
        int l = i ^ j;
        if (l > i) {
          float a = srt[i], b = srt[l];
          if ((a > b) == ((i & k2) == 0)) { srt[i] = b; srt[l] = a; }
        }
      }
      __syncthreads();
    }
  }
  float thr = srt[NPG - kk];
#pragma unroll
  for (int q = 0; q < 4; ++q) {
    int n = t + q * 256;
    float s = sc[n];
    bool sel = (gate[(g << 10) + n] != 0.f) && (s >= thr);
    gate[(g << 10) + n] = sel ? tanhf(s) : 0.f;
  }
}

// ---------------------------------------------------------------------------
// global mean pool of gate-weighted rows (divisor exactly K3), MLP, log_softmax
__global__ __launch_bounds__(128) void final_kernel(const float* __restrict__ X,
                                                    const float* __restrict__ gate,
                                                    const float* __restrict__ Wf1,
                                                    const float* __restrict__ bf1,
                                                    const float* __restrict__ Wf2,
                                                    const float* __restrict__ bf2,
                                                    float* __restrict__ out) {
  __shared__ float gs[NPG];
  __shared__ float pl[HD];
  __shared__ float h1[64];
  __shared__ float lg[10];
  __shared__ float red[2];
  int g = blockIdx.x, t = threadIdx.x;
  for (int i = t; i < NPG; i += 128) gs[i] = gate[(g << 10) + i];
  __syncthreads();
  size_t base = (size_t)g * NPG * HD;
  float s = 0.f;
  for (int r = 0; r < NPG; ++r) s += X[base + (size_t)r * HD + t] * gs[r];
  pl[t] = s / (float)KS3;
  __syncthreads();
  if (t < 64) {
    float h = bf1[t];
    for (int f = 0; f < HD; ++f) h += pl[f] * Wf1[t * HD + f];
    h1[t] = fmaxf(h, 0.f);
  }
  __syncthreads();
  if (t < 10) {
    float z = bf2[t];
    for (int j = 0; j < 64; ++j) z += h1[j] * Wf2[t * 64 + j];
    lg[t] = z;
  }
  __syncthreads();
  if (t == 0) {
    float m = lg[0];
    for (int c = 1; c < 10; ++c) m = fmaxf(m, lg[c]);
    float ssum = 0.f;
    for (int c = 0; c < 10; ++c) ssum += expf(lg[c] - m);
    red[0] = m; red[1] = logf(ssum);
  }
  __syncthreads();
  if (t < 10) out[g * 10 + t] = lg[t] - red[0] - red[1];
}

// ---------------------------------------------------------------------------
extern "C" void kernel_launch(void* const* d_in, const int* in_sizes, int n_in,
                              void* d_out, int out_size, void* d_ws, size_t ws_size,
                              hipStream_t stream) {
  const float* x  = (const float*)d_in[0];
  int* ei         = (int*)d_in[1];          // src half becomes CSR after csr_build
  const float* Wl[3]  = {(const float*)d_in[2], (const float*)d_in[6],  (const float*)d_in[10]};
  const float* blv[3] = {(const float*)d_in[3], (const float*)d_in[7],  (const float*)d_in[11]};
  const float* Wr[3]  = {(const float*)d_in[4], (const float*)d_in[8],  (const float*)d_in[12]};
  const float* wp[3]  = {(const float*)d_in[5], (const float*)d_in[9],  (const float*)d_in[13]};
  const float* Wf1 = (const float*)d_in[14];
  const float* bf1 = (const float*)d_in[15];
  const float* Wf2 = (const float*)d_in[16];
  const float* bf2 = (const float*)d_in[17];
  float* out = (float*)d_out;

  // workspace: bufA (64MB) | bufB (64MB) | gate (512KB) | score (512KB)
  float* bufA  = (float*)d_ws;
  float* bufB  = bufA + (size_t)NN * HD;
  float* gate  = bufB + (size_t)NN * HD;
  float* score = gate + NN;

  init_gate<<<NN / 256, 256, 0, stream>>>(gate);
  csr_build<<<NGPH, 512, 0, stream>>>(ei);

  // L1: x -> mean(bufA) -> gemm in-place bufA (+score) -> topk (gate only)
  agg2_kernel<<<NN / 8, 256, 0, stream>>>(x, ei, gate, bufA);
  gemm_mfma<<<NN / 128, 256, 0, stream>>>(bufA, x, Wl[0], Wr[0], blv[0], wp[0], gate, bufA, score);
  topk_kernel<<<NGPH, 256, 0, stream>>>(score, gate, wp[0], KS1);
  // L2
  agg2_kernel<<<NN / 8, 256, 0, stream>>>(bufA, ei, gate, bufB);
  gemm_mfma<<<NN / 128, 256, 0, stream>>>(bufB, bufA, Wl[1], Wr[1], blv[1], wp[1], gate, bufB, score);
  topk_kernel<<<NGPH, 256, 0, stream>>>(score, gate, wp[1], KS2);
  // L3
  agg2_kernel<<<NN / 8, 256, 0, stream>>>(bufB, ei, gate, bufA);
  gemm_mfma<<<NN / 128, 256, 0, stream>>>(bufA, bufB, Wl[2], Wr[2], blv[2], wp[2], gate, bufA, score);
  topk_kernel<<<NGPH, 256, 0, stream>>>(score, gate, wp[2], KS3);

  final_kernel<<<NGPH, 128, 0, stream>>>(bufA, gate, Wf1, bf1, Wf2, bf2, out);
}